// Round 13
// baseline (32.561 us; speedup 1.0000x reference)
//
#include <hip/hip_runtime.h>
#include <math.h>

#define LL 4096
#define BB 2048
#define NT 512
#define ROWS 4                 // rows per persistent block
#define GRID (BB / ROWS)       // 512 blocks -> 2 per CU
#define ALPHA 1.0f
#define BETA 0.5f
#define NEG_INF (-__builtin_inff())
#define POS_INF (__builtin_inff())

// Padded LDS layout: logical position i in [-24, LL+23] lives at i + (i>>3) + 27.
// IDX(8t + d) == 9t + (d + (d>>3) + 27) -> with base = arr + 9t, every offset the
// eval needs is a compile-time immediate; lane stride 9 (odd) => max 2-way alias.
#define SPSZ 4672
#define OFS(d) ((d) + ((d) >> 3) + 27)

// ---- DPP wave64 sum reduction (VALU pipe) ----
template <int CTRL, int RM>
__device__ __forceinline__ float dpp_addf(float v) {
    int s = __builtin_amdgcn_update_dpp(0, __float_as_int(v), CTRL, RM, 0xf, true);
    return v + __int_as_float(s);
}
__device__ __forceinline__ float wredf(float v) {
    v = dpp_addf<0x111, 0xf>(v);   // row_shr:1
    v = dpp_addf<0x112, 0xf>(v);   // row_shr:2
    v = dpp_addf<0x114, 0xf>(v);   // row_shr:4
    v = dpp_addf<0x118, 0xf>(v);   // row_shr:8
    v = dpp_addf<0x142, 0xa>(v);   // row_bcast:15
    v = dpp_addf<0x143, 0xc>(v);   // row_bcast:31
    return v;                      // total in lane 63
}

// LDS-only barrier: orders ds ops block-wide WITHOUT draining vmcnt, so the
// next row's in-flight global prefetch loads survive across it.
__device__ __forceinline__ void barrier_lds() {
    asm volatile("s_waitcnt lgkmcnt(0)" ::: "memory");
    __builtin_amdgcn_s_barrier();
}

__global__ __launch_bounds__(NT, 4) void row_kernel(const float* __restrict__ gA,
                                                    const float* __restrict__ gB,
                                                    float4* __restrict__ ws4) {
    __shared__ float sS[SPSZ];
    __shared__ float sP[SPSZ];

    const int t = threadIdx.x;
    float* const Sb = sS + 9 * t;
    float* const Pb = sP + 9 * t;

    // ---- -inf margins, written once (scans never touch them) ----
    if (t < 24) {
        int i = t - 24;
        int p = i + (i >> 3) + 27;
        sS[p] = NEG_INF; sP[p] = NEG_INF;
    } else if (t >= NT - 24) {
        int i = LL + (t - (NT - 24));
        int p = i + (i >> 3) + 27;
        sS[p] = NEG_INF; sP[p] = NEG_INF;
    }

    auto load2 = [&](float (&xA)[8], float (&xB)[8], int row) {
        const float4* a4 = (const float4*)(gA + (size_t)row * LL);
        const float4* b4 = (const float4*)(gB + (size_t)row * LL);
        float4 v0 = a4[2 * t], v1 = a4[2 * t + 1];
        xA[0] = v0.x; xA[1] = v0.y; xA[2] = v0.z; xA[3] = v0.w;
        xA[4] = v1.x; xA[5] = v1.y; xA[6] = v1.z; xA[7] = v1.w;
        float4 u0 = b4[2 * t], u1 = b4[2 * t + 1];
        xB[0] = u0.x; xB[1] = u0.y; xB[2] = u0.z; xB[3] = u0.w;
        xB[4] = u1.x; xB[5] = u1.y; xB[6] = u1.z; xB[7] = u1.w;
    };

    auto scan = [&](const float (&x)[8]) -> float {
        float pp[8], ss[8];
        pp[0] = x[0];
#pragma unroll
        for (int j = 1; j < 8; ++j) pp[j] = fmaxf(pp[j - 1], x[j]);
        ss[7] = x[7];
#pragma unroll
        for (int j = 6; j >= 0; --j) ss[j] = fmaxf(ss[j + 1], x[j]);
#pragma unroll
        for (int j = 0; j < 8; ++j) {
            Pb[j + 27] = pp[j];
            Sb[j + 27] = ss[j];
        }
        return pp[7];
    };

    auto eval = [&](const float (&x)[8], float cmax, unsigned& m10, int& cnt) {
        const float Cm2 = Pb[OFS(-9)];
        const float Cm1 = Pb[OFS(-1)];
        const float Cp1 = Pb[OFS(15)];
        const float Cp2 = Pb[OFS(23)];
        const float f1 = fmaxf(Cm1, cmax);
        const float f2 = fmaxf(cmax, Cp1);
        const float g2 = fmaxf(f1, Cp1);
        const float g1 = fmaxf(g2, Cm2);
        const float g3 = fmaxf(g2, Cp2);
        const float xm1 = (t == 0)      ? POS_INF : Sb[OFS(-1)];
        const float xp1 = (t == NT - 1) ? POS_INF : Pb[OFS(8)];
        m10 = 0u;
#pragma unroll
        for (int j = 0; j < 8; ++j) {
            float xi = x[j];
            float xl = (j > 0) ? x[j - 1] : xm1;
            float xr = (j < 7) ? x[j + 1] : xp1;
            bool lm = (xi > xl) && (xi > xr);
            float a19 = Sb[OFS(j - 9)];
            float b19 = Pb[OFS(j + 9)];
            float a39 = Sb[OFS(j - 19)];
            float b39 = Pb[OFS(j + 19)];
            float mid19 = (j == 0) ? f1 : ((j == 7) ? f2 : cmax);
            float mid39 = (j <= 2) ? g1 : ((j <= 4) ? g2 : g3);
            float p19 = fmaxf(fmaxf(a19, b19), mid19);
            float p39 = fmaxf(fmaxf(a39, b39), mid39);
            if (lm && xi >= p19) m10 |= (1u << j);
            cnt += (int)__popcll(__ballot(lm && (xi >= p39)));   // SALU, wave-uniform
        }
    };

    auto process = [&](const float (&xA)[8], const float (&xB)[8], int row) {
        float se = 0.f, dtp = 0.f, na = 0.f, nb = 0.f;
#pragma unroll
        for (int j = 0; j < 8; ++j) {
            float d = xA[j] - xB[j];
            se  += d * d;
            dtp += xA[j] * xB[j];
            na  += xA[j] * xA[j];
            nb  += xB[j] * xB[j];
        }
        se = wredf(se); dtp = wredf(dtp); na = wredf(na); nb = wredf(nb);

        unsigned mA, mB;
        int cntA = 0, cntB = 0;
        float cmA = scan(xA);
        barrier_lds();             // scans visible
        eval(xA, cmA, mA, cntA);
        barrier_lds();             // A-reads done before B scan overwrites
        float cmB = scan(xB);
        barrier_lds();
        eval(xB, cmB, mB, cntB);

        float p2p = 0.f;
#pragma unroll
        for (int j = 0; j < 8; ++j) {
            float av = ((mA >> j) & 1u) ? xA[j] : 0.f;
            float bv = ((mB >> j) & 1u) ? xB[j] : 0.f;
            float d = av - bv;
            p2p += d * d;
        }
        p2p = wredf(p2p);          // only tail DPP chain (counts are uniform)

        if ((t & 63) == 63) {
            const int w = t >> 6;
            ws4[(size_t)row * 16 + w * 2 + 0] = make_float4(se, dtp, na, nb);
            ws4[(size_t)row * 16 + w * 2 + 1] =
                make_float4(p2p, (float)(cntA * 4096 + cntB), 0.f, 0.f);
        }
        barrier_lds();             // B-reads done before next row's scan
    };

    // ---- rolling register double-buffer over ROWS rows ----
    float a0[8], b0[8], a1[8], b1[8];
    load2(a0, b0, blockIdx.x);
#pragma unroll
    for (int r = 0; r < ROWS; ++r) {
        const int row = blockIdx.x + r * GRID;
        if (r + 1 < ROWS) {
            if (r & 1) load2(a0, b0, row + GRID);   // refill the consumed buffer
            else       load2(a1, b1, row + GRID);
        }
        if (r & 1) process(a1, b1, row);
        else       process(a0, b0, row);
    }
}

__global__ __launch_bounds__(256) void reduce_kernel(const float4* __restrict__ ws4,
                                                     float* __restrict__ out) {
    __shared__ float red[4][4];
    const int r = blockIdx.x * 256 + threadIdx.x;    // 8x256 -> 2048 rows
    float s0 = 0, s1 = 0, s2 = 0, s3 = 0, s4 = 0, s5 = 0;
#pragma unroll
    for (int w = 0; w < 8; ++w) {
        float4 u = ws4[(size_t)r * 16 + w * 2 + 0];
        float4 v = ws4[(size_t)r * 16 + w * 2 + 1];
        s0 += u.x; s1 += u.y; s2 += u.z; s3 += u.w;
        s4 += v.x; s5 += v.y;
    }
    int packed = (int)s5;
    int ca = packed >> 12, cb = packed & 4095;
    float mse_i = s0 * (1.0f / LL);
    float cos_i = s1 / (sqrtf(s2) * sqrtf(s3));
    float p2p_i = s4 * (1.0f / LL);
    float custom_i = (ca != cb) ? (mse_i * ALPHA) : (p2p_i * BETA);
    const float invB = 1.0f / (float)BB;
    float v0 = mse_i * invB + custom_i;   // -> total_loss
    float v1 = cos_i * invB;              // -> mean cosine
    float v2 = p2p_i;                     // -> p2p_loss
    float v3 = mse_i * invB;              // -> mse_loss
    v0 = wredf(v0); v1 = wredf(v1); v2 = wredf(v2); v3 = wredf(v3);
    int w = threadIdx.x >> 6, lane = threadIdx.x & 63;
    if (lane == 63) { red[w][0] = v0; red[w][1] = v1; red[w][2] = v2; red[w][3] = v3; }
    __syncthreads();
    if (threadIdx.x == 0) {
        float a0 = 0, a1 = 0, a2 = 0, a3 = 0;
#pragma unroll
        for (int i = 0; i < 4; ++i) {
            a0 += red[i][0]; a1 += red[i][1]; a2 += red[i][2]; a3 += red[i][3];
        }
        atomicAdd(out + 0, a0);   // 8 blocks x 4 adds — negligible contention
        atomicAdd(out + 1, a1);
        atomicAdd(out + 2, a2);
        atomicAdd(out + 3, a3);
    }
}

extern "C" void kernel_launch(void* const* d_in, const int* in_sizes, int n_in,
                              void* d_out, int out_size, void* d_ws, size_t ws_size,
                              hipStream_t stream) {
    const float* inA = (const float*)d_in[0];   // in_signal
    const float* inB = (const float*)d_in[1];   // ref_signal
    float* out = (float*)d_out;
    float4* ws4 = (float4*)d_ws;                // 2048 x 16 float4 = 512 KiB partials

    hipMemsetAsync(out, 0, out_size * sizeof(float), stream);
    hipLaunchKernelGGL(row_kernel, dim3(GRID), dim3(NT), 0, stream, inA, inB, ws4);
    hipLaunchKernelGGL(reduce_kernel, dim3(8), dim3(256), 0, stream, ws4, out);
}